// Round 7
// baseline (85.107 us; speedup 1.0000x reference)
//
#include <hip/hip_runtime.h>

// X [B=8, L=4096, D=1024] fp32.  O = (L*X - colsum_over_L) / (L-1).
// Two-tile software pipeline per block: tiles are 16 cols = one 64B line per
// row, so tile A and tile B occupy disjoint cache lines. Stores of tile A are
// in flight while loads of tile B stream -> mixed read+write HBM traffic for
// the middle ~50% of the kernel (copy-rate instead of unidirectional rate).
constexpr int Bn = 8;
constexpr int Ln = 4096;
constexpr int Dn = 1024;

constexpr int TD  = 16;          // cols per tile = 64B per row (one cache line)
constexpr int NT  = 1024;        // 16 waves per block
constexpr int QPB = TD / 4;      // 4 float4-quads per row of a tile
constexpr int RPI = NT / QPB;    // 256 rows per load iteration
constexpr int NIT = Ln / RPI;    // 16 staged f32x4 per thread per tile
constexpr int NW  = NT / 64;     // 16 waves

typedef float f32x4 __attribute__((ext_vector_type(4)));

__global__ __launch_bounds__(NT) void ordering_pipe2_kernel(
    const float* __restrict__ X, float* __restrict__ O) {
    const int tid  = threadIdx.x;
    const int lane = tid & 63;
    const int w    = tid >> 6;           // wave id 0..15
    const int q    = tid & (QPB - 1);    // quad within tile row
    const int g    = tid >> 2;           // row group 0..255

    const int gt0 = blockIdx.x * 2;      // even global tile id; pair shares batch
    const int b   = gt0 >> 6;            // 64 tiles per batch
    const int t0  = gt0 & 63;
    const size_t base0 = (size_t)b * Ln * Dn + (size_t)t0 * TD
                       + (size_t)q * 4 + (size_t)g * Dn;
    const size_t base1 = base0 + TD;     // adjacent tile: next 64B column line
    constexpr size_t STR = (size_t)RPI * Dn;

    const float Lf  = (float)Ln;
    const float inv = 1.0f / (float)(Ln - 1);

    __shared__ f32x4 red[2][NW][QPB];    // 2 KiB, one buffer per tile

    // ================= tile A: load -> reduce -> store =================
    f32x4 vA[NIT];
#pragma unroll
    for (int k = 0; k < NIT; ++k)
        vA[k] = *reinterpret_cast<const f32x4*>(X + base0 + (size_t)k * STR);

    f32x4 p0 = (f32x4)0.f, p1 = (f32x4)0.f, p2 = (f32x4)0.f, p3 = (f32x4)0.f;
#pragma unroll
    for (int k = 0; k < NIT; k += 4) {
        p0 += vA[k + 0]; p1 += vA[k + 1]; p2 += vA[k + 2]; p3 += vA[k + 3];
    }
    f32x4 accA = (p0 + p1) + (p2 + p3);
#pragma unroll
    for (int m = QPB; m <= 32; m <<= 1) {
        f32x4 o;
        o.x = __shfl_xor(accA.x, m);
        o.y = __shfl_xor(accA.y, m);
        o.z = __shfl_xor(accA.z, m);
        o.w = __shfl_xor(accA.w, m);
        accA += o;
    }
    if (lane < QPB) red[0][w][q] = accA;
    // raw barrier: only drain LDS, NOT vmcnt (keep global memory ops in flight)
    asm volatile("s_waitcnt lgkmcnt(0)" ::: "memory");
    __builtin_amdgcn_s_barrier();
    asm volatile("" ::: "memory");
    f32x4 totA = (f32x4)0.f;
#pragma unroll
    for (int ww = 0; ww < NW; ++ww) totA += red[0][ww][q];

    // keep staged values in registers (defeat load rematerialization, cf. R6)
#pragma unroll
    for (int k = 0; k < NIT; ++k) asm volatile("" : "+v"(vA[k]));
#pragma unroll
    for (int k = 0; k < NIT; ++k)
        *reinterpret_cast<f32x4*>(O + base0 + (size_t)k * STR) =
            (Lf * vA[k] - totA) * inv;

    // pin tile-B loads below tile-A stores so HBM sees mixed traffic
    __builtin_amdgcn_sched_barrier(0);

    // ================= tile B: load -> reduce -> store =================
    f32x4 vB[NIT];
#pragma unroll
    for (int k = 0; k < NIT; ++k)
        vB[k] = *reinterpret_cast<const f32x4*>(X + base1 + (size_t)k * STR);

    f32x4 r0 = (f32x4)0.f, r1 = (f32x4)0.f, r2 = (f32x4)0.f, r3 = (f32x4)0.f;
#pragma unroll
    for (int k = 0; k < NIT; k += 4) {
        r0 += vB[k + 0]; r1 += vB[k + 1]; r2 += vB[k + 2]; r3 += vB[k + 3];
    }
    f32x4 accB = (r0 + r1) + (r2 + r3);
#pragma unroll
    for (int m = QPB; m <= 32; m <<= 1) {
        f32x4 o;
        o.x = __shfl_xor(accB.x, m);
        o.y = __shfl_xor(accB.y, m);
        o.z = __shfl_xor(accB.z, m);
        o.w = __shfl_xor(accB.w, m);
        accB += o;
    }
    if (lane < QPB) red[1][w][q] = accB;
    asm volatile("s_waitcnt lgkmcnt(0)" ::: "memory");
    __builtin_amdgcn_s_barrier();
    asm volatile("" ::: "memory");
    f32x4 totB = (f32x4)0.f;
#pragma unroll
    for (int ww = 0; ww < NW; ++ww) totB += red[1][ww][q];

#pragma unroll
    for (int k = 0; k < NIT; ++k) asm volatile("" : "+v"(vB[k]));
#pragma unroll
    for (int k = 0; k < NIT; ++k)
        *reinterpret_cast<f32x4*>(O + base1 + (size_t)k * STR) =
            (Lf * vB[k] - totB) * inv;
}

extern "C" void kernel_launch(void* const* d_in, const int* in_sizes, int n_in,
                              void* d_out, int out_size, void* d_ws, size_t ws_size,
                              hipStream_t stream) {
    (void)in_sizes; (void)n_in; (void)d_ws; (void)ws_size; (void)out_size;
    const float* X = (const float*)d_in[0];
    float* O = (float*)d_out;
    const int grid = Bn * (Dn / TD) / 2;   // 256 blocks, 2 tiles each
    ordering_pipe2_kernel<<<grid, NT, 0, stream>>>(X, O);
}